// Round 1
// baseline (4546.541 us; speedup 1.0000x reference)
//
#include <hip/hip_runtime.h>

#define GN 64
#define N_TOTAL (GN * GN * GN)   // 262144
#define KOFF 24

// 24 Manhattan-radius-2 offsets, sorted by linear delta (dx*4096 + dy*64 + dz)
// ascending. List is symmetric under negation: inv(k) = 23 - k.
__device__ constexpr int DLc[KOFF] = {
    -8192, -4160, -4097, -4096, -4095, -4032,
     -128,   -65,   -64,   -63,    -2,    -1,
        1,     2,    63,    64,    65,   128,
     4032,  4095,  4096,  4097,  4160,  8192};
__device__ constexpr int DXc[KOFF] = {
    -2, -1, -1, -1, -1, -1, 0, 0, 0, 0, 0, 0,
     0,  0,  0,  0,  0,  0, 1, 1, 1, 1, 1, 2};
__device__ constexpr int DYc[KOFF] = {
     0, -1,  0,  0,  0,  1, -2, -1, -1, -1, 0, 0,
     0,  0,  1,  1,  1,  2, -1,  0,  0,  0, 1, 0};
__device__ constexpr int DZc[KOFF] = {
     0,  0, -1,  0,  1,  0,  0, -1,  0,  1, -2, -1,
     1,  2, -1,  0,  1,  0,  0, -1,  0,  1,  0,  0};

// Re-pack COO edge_values into dense (N, 24) row-major layout.
// delta = col - row uniquely identifies the offset (no wrap: both endpoints
// in-bounds, delta is the exact linearized offset).
__global__ void scatter_w_kernel(const float* __restrict__ ev,
                                 const int* __restrict__ rows,
                                 const int* __restrict__ cols,
                                 float* __restrict__ w, int E) {
    int e = blockIdx.x * blockDim.x + threadIdx.x;
    if (e >= E) return;
    int r = rows[e];
    int dl = cols[e] - r;
    int k = 0;
#pragma unroll
    for (int i = 0; i < KOFF; i++)
        if (DLc[i] == dl) k = i;
    w[r * KOFF + k] = ev[e];
}

// One simulation step, fused: syn gather + neuron update + STDP.
// w double-buffered: reads w_old (all rows), writes w_new (own row only).
__global__ __launch_bounds__(256) void step_kernel(
    const float* __restrict__ xext,      // external_input + t*N
    const float* __restrict__ w_old,
    float* __restrict__ w_new,
    const float* __restrict__ prev,      // out of previous step
    float* __restrict__ out,
    float* __restrict__ v,
    float* __restrict__ spk,             // d_out + t*N
    int t) {
#pragma clang fp contract(off)
    int j = blockIdx.x * 256 + threadIdx.x;
    int z = j & 63, y = (j >> 6) & 63, x = j >> 12;

    float pv[KOFF];
    float syn = 0.0f;
    if (t == 0) {
        // prev == 0 at step 0; buffers unread (poisoned) -> skip gather.
#pragma unroll
        for (int k = 0; k < KOFF; k++) pv[k] = 0.0f;
    } else {
#pragma unroll
        for (int k = 0; k < KOFF; k++) {
            int nx = x + DXc[k], ny = y + DYc[k], nz = z + DZc[k];
            bool ok = ((unsigned)nx < 64u) & ((unsigned)ny < 64u) &
                      ((unsigned)nz < 64u);
            int nb = j + DLc[k];
            float p = 0.0f, wv = 0.0f;
            if (ok) {
                p = prev[nb];
                wv = w_old[nb * KOFF + (23 - k)];  // edge (nb -> j)
            }
            pv[k] = p;
            float m = wv * p;     // contract(off): mul then add, like numpy
            syn = syn + m;        // ascending-row order == segment_sum order
        }
    }

    float myv = (t == 0) ? -65.0f : v[j];
    const float decay = expf(-1.0f / 20.0f);
    float I = syn + xext[j];
    float vn = (myv * decay) + (I * (1.0f - decay));
    float spike = (vn >= -50.0f) ? 1.0f : 0.0f;
    float inhib = (vn <= -70.0f) ? 1.0f : 0.0f;
    float sg = 1.0f / (1.0f + expf(-((vn - (-60.0f)) * 0.5f)));
    float o = spike + ((1.0f - spike) * (1.0f - inhib)) * sg;
    v[j] = (vn * (1.0f - spike)) + (spike * (-65.0f));
    out[j] = o;
    spk[j] = spike;

    // STDP on row j's edges: pre = prev[col] = pv[k], post = out[j] = o.
    // Invalid slots: wv==0 && pv==0 -> dw==0 -> stays 0. No masking needed.
#pragma unroll
    for (int k = 0; k < KOFF; k++) {
        float wv = w_old[j * KOFF + k];
        float nw;
        if (t == 0) {
            nw = wv;  // reference skips plasticity at step 0
        } else {
            float pre = pv[k];
            float a = (0.01f * pre) * o;
            float b = (0.005f * pre) * (1.0f - o);
            float c = 1e-5f * wv;
            float dw = (a - b) - c;
            nw = wv + dw;
            nw = fminf(fmaxf(nw, 0.0f), 1.0f);
        }
        w_new[j * KOFF + k] = nw;
    }
}

extern "C" void kernel_launch(void* const* d_in, const int* in_sizes, int n_in,
                              void* d_out, int out_size, void* d_ws, size_t ws_size,
                              hipStream_t stream) {
    const float* xext = (const float*)d_in[0];
    const float* ev   = (const float*)d_in[1];
    const int* rows   = (const int*)d_in[2];
    const int* cols   = (const int*)d_in[3];
    float* spk = (float*)d_out;

    int T = in_sizes[0] / N_TOTAL;   // 50
    int E = in_sizes[1];             // ~6.1M edges

    // Workspace layout: w0 | w1 | P0 | P1 | v  -> (2*24 + 3) * N floats ≈ 53.5 MB
    float* w0 = (float*)d_ws;
    float* w1 = w0 + (size_t)N_TOTAL * KOFF;
    float* P0 = w1 + (size_t)N_TOTAL * KOFF;
    float* P1 = P0 + N_TOTAL;
    float* vb = P1 + N_TOTAL;

    hipMemsetAsync(w0, 0, (size_t)N_TOTAL * KOFF * sizeof(float), stream);
    scatter_w_kernel<<<(E + 255) / 256, 256, 0, stream>>>(ev, rows, cols, w0, E);

    for (int t = 0; t < T; t++) {
        const float* wo = (t & 1) ? w1 : w0;
        float*       wn = (t & 1) ? w0 : w1;
        const float* pr = (t & 1) ? P1 : P0;
        float*       po = (t & 1) ? P0 : P1;
        step_kernel<<<N_TOTAL / 256, 256, 0, stream>>>(
            xext + (size_t)t * N_TOTAL, wo, wn, pr, po, vb,
            spk + (size_t)t * N_TOTAL, t);
    }
}

// Round 2
// 960.535 us; speedup vs baseline: 4.7333x; 4.7333x over previous
//
#include <hip/hip_runtime.h>

#define GN 64
#define N_TOTAL (GN * GN * GN)   // 262144
#define KOFF 24

// 24 Manhattan-radius-2 offsets, sorted by linear delta (dx*4096 + dy*64 + dz)
// ascending. List is symmetric under negation: inv(k) = 23 - k.
__device__ constexpr int DLc[KOFF] = {
    -8192, -4160, -4097, -4096, -4095, -4032,
     -128,   -65,   -64,   -63,    -2,    -1,
        1,     2,    63,    64,    65,   128,
     4032,  4095,  4096,  4097,  4160,  8192};
__device__ constexpr int DXc[KOFF] = {
    -2, -1, -1, -1, -1, -1, 0, 0, 0, 0, 0, 0,
     0,  0,  0,  0,  0,  0, 1, 1, 1, 1, 1, 2};
__device__ constexpr int DYc[KOFF] = {
     0, -1,  0,  0,  0,  1, -2, -1, -1, -1, 0, 0,
     0,  0,  1,  1,  1,  2, -1,  0,  0,  0, 1, 0};
__device__ constexpr int DZc[KOFF] = {
     0,  0, -1,  0,  1,  0,  0, -1,  0,  1, -2, -1,
     1,  2, -1,  0,  1,  0,  0, -1,  0,  1,  0,  0};

// Re-pack COO edge_values into PLANE-MAJOR (24, N) layout: w[k*N + row].
// delta = col - row uniquely identifies the offset slot k.
__global__ void scatter_w_kernel(const float* __restrict__ ev,
                                 const int* __restrict__ rows,
                                 const int* __restrict__ cols,
                                 float* __restrict__ w, int E) {
    int e = blockIdx.x * blockDim.x + threadIdx.x;
    if (e >= E) return;
    int r = rows[e];
    int dl = cols[e] - r;
    int k = 0;
#pragma unroll
    for (int i = 0; i < KOFF; i++)
        if (DLc[i] == dl) k = i;
    w[k * N_TOTAL + r] = ev[e];
}

// One simulation step, fused: syn gather + neuron update + STDP.
// w double-buffered: reads w_old (all planes), writes w_new (own column j).
// Plane-major layout -> every w access is wave-coalesced (lane j -> addr j*4).
__global__ __launch_bounds__(256) void step_kernel(
    const float* __restrict__ xext,      // external_input + t*N
    const float* __restrict__ w_old,
    float* __restrict__ w_new,
    const float* __restrict__ prev,      // out of previous step
    float* __restrict__ out,
    float* __restrict__ v,
    float* __restrict__ spk,             // d_out + t*N
    int t) {
#pragma clang fp contract(off)
    int j = blockIdx.x * 256 + threadIdx.x;
    int z = j & 63, y = (j >> 6) & 63, x = j >> 12;

    float pv[KOFF];
    float syn = 0.0f;
    if (t == 0) {
        // prev == 0 at step 0; buffers unread (poisoned) -> skip gather.
#pragma unroll
        for (int k = 0; k < KOFF; k++) pv[k] = 0.0f;
    } else {
#pragma unroll
        for (int k = 0; k < KOFF; k++) {
            int nx = x + DXc[k], ny = y + DYc[k], nz = z + DZc[k];
            bool ok = ((unsigned)nx < 64u) & ((unsigned)ny < 64u) &
                      ((unsigned)nz < 64u);
            int nb = j + DLc[k];
            float p = 0.0f, wv = 0.0f;
            if (ok) {
                p = prev[nb];
                wv = w_old[(23 - k) * N_TOTAL + nb];  // edge (nb -> j)
            }
            pv[k] = p;
            float m = wv * p;     // contract(off): mul then add, like numpy
            syn = syn + m;        // ascending-row order == segment_sum order
        }
    }

    float myv = (t == 0) ? -65.0f : v[j];
    const float decay = expf(-1.0f / 20.0f);
    float I = syn + xext[j];
    float vn = (myv * decay) + (I * (1.0f - decay));
    float spike = (vn >= -50.0f) ? 1.0f : 0.0f;
    float inhib = (vn <= -70.0f) ? 1.0f : 0.0f;
    float sg = 1.0f / (1.0f + expf(-((vn - (-60.0f)) * 0.5f)));
    float o = spike + ((1.0f - spike) * (1.0f - inhib)) * sg;
    v[j] = (vn * (1.0f - spike)) + (spike * (-65.0f));
    out[j] = o;
    spk[j] = spike;

    // STDP on row j's edges: pre = prev[col] = pv[k], post = out[j] = o.
    // Invalid slots: wv==0 && pv==0 -> dw==0 -> stays 0. No masking needed.
#pragma unroll
    for (int k = 0; k < KOFF; k++) {
        float wv = w_old[k * N_TOTAL + j];
        float nw;
        if (t == 0) {
            nw = wv;  // reference skips plasticity at step 0
        } else {
            float pre = pv[k];
            float a = (0.01f * pre) * o;
            float b = (0.005f * pre) * (1.0f - o);
            float c = 1e-5f * wv;
            float dw = (a - b) - c;
            nw = wv + dw;
            nw = fminf(fmaxf(nw, 0.0f), 1.0f);
        }
        w_new[k * N_TOTAL + j] = nw;
    }
}

extern "C" void kernel_launch(void* const* d_in, const int* in_sizes, int n_in,
                              void* d_out, int out_size, void* d_ws, size_t ws_size,
                              hipStream_t stream) {
    const float* xext = (const float*)d_in[0];
    const float* ev   = (const float*)d_in[1];
    const int* rows   = (const int*)d_in[2];
    const int* cols   = (const int*)d_in[3];
    float* spk = (float*)d_out;

    int T = in_sizes[0] / N_TOTAL;   // 50
    int E = in_sizes[1];             // ~6.1M edges

    // Workspace layout: w0 | w1 | P0 | P1 | v  -> (2*24 + 3) * N floats ≈ 53.5 MB
    float* w0 = (float*)d_ws;
    float* w1 = w0 + (size_t)N_TOTAL * KOFF;
    float* P0 = w1 + (size_t)N_TOTAL * KOFF;
    float* P1 = P0 + N_TOTAL;
    float* vb = P1 + N_TOTAL;

    hipMemsetAsync(w0, 0, (size_t)N_TOTAL * KOFF * sizeof(float), stream);
    scatter_w_kernel<<<(E + 255) / 256, 256, 0, stream>>>(ev, rows, cols, w0, E);

    for (int t = 0; t < T; t++) {
        const float* wo = (t & 1) ? w1 : w0;
        float*       wn = (t & 1) ? w0 : w1;
        const float* pr = (t & 1) ? P1 : P0;
        float*       po = (t & 1) ? P0 : P1;
        step_kernel<<<N_TOTAL / 256, 256, 0, stream>>>(
            xext + (size_t)t * N_TOTAL, wo, wn, pr, po, vb,
            spk + (size_t)t * N_TOTAL, t);
    }
}

// Round 3
// 944.328 us; speedup vs baseline: 4.8146x; 1.0172x over previous
//
#include <hip/hip_runtime.h>

#define GN 64
#define N_TOTAL (GN * GN * GN)   // 262144
#define KOFF 24

// 24 Manhattan-radius-2 offsets, sorted by linear delta (dx*4096 + dy*64 + dz)
// ascending. List is symmetric under negation: inv(k) = 23 - k.
__device__ constexpr int DLc[KOFF] = {
    -8192, -4160, -4097, -4096, -4095, -4032,
     -128,   -65,   -64,   -63,    -2,    -1,
        1,     2,    63,    64,    65,   128,
     4032,  4095,  4096,  4097,  4160,  8192};
__device__ constexpr int DXc[KOFF] = {
    -2, -1, -1, -1, -1, -1, 0, 0, 0, 0, 0, 0,
     0,  0,  0,  0,  0,  0, 1, 1, 1, 1, 1, 2};
__device__ constexpr int DYc[KOFF] = {
     0, -1,  0,  0,  0,  1, -2, -1, -1, -1, 0, 0,
     0,  0,  1,  1,  1,  2, -1,  0,  0,  0, 1, 0};
__device__ constexpr int DZc[KOFF] = {
     0,  0, -1,  0,  1,  0,  0, -1,  0,  1, -2, -1,
     1,  2, -1,  0,  1,  0,  0, -1,  0,  1,  0,  0};

// Deterministic re-pack of ev into PLANE-MAJOR (24, N): w[k*N + row].
// Edges are lexsorted (row asc, col asc); for a row, valid cols are
// row + DL[k] in ascending k. Row's start offset S(row) = sum over offsets of
// |{r' in valid-box : lin(r') < lin(row)}| -- closed-form box counting.
// No rows/cols reads, no memset, fully coalesced writes.
__global__ __launch_bounds__(256) void pack_w_kernel(
    const float* __restrict__ ev, float* __restrict__ w) {
    int j = blockIdx.x * 256 + threadIdx.x;
    int z = j & 63, y = (j >> 6) & 63, x = j >> 12;

    int S = 0;
#pragma unroll
    for (int k = 0; k < KOFF; k++) {
        int dx = DXc[k], dy = DYc[k], dz = DZc[k];
        int x0 = max(0, -dx), x1 = min(64, 64 - dx);
        int y0 = max(0, -dy), y1 = min(64, 64 - dy);
        int z0 = max(0, -dz), z1 = min(64, 64 - dz);
        int ny = y1 - y0, nz = z1 - z0;
        int nxb = max(0, min(x, x1) - x0);
        int cnt = nxb * ny * nz;
        if (x >= x0 && x < x1) {
            cnt += max(0, min(y, y1) - y0) * nz;
            if (y >= y0 && y < y1)
                cnt += max(0, min(z, z1) - z0);
        }
        S += cnt;
    }

    int idx = 0;
#pragma unroll
    for (int k = 0; k < KOFF; k++) {
        int nx = x + DXc[k], ny = y + DYc[k], nz = z + DZc[k];
        bool ok = ((unsigned)nx < 64u) & ((unsigned)ny < 64u) &
                  ((unsigned)nz < 64u);
        float wv = 0.0f;
        if (ok) { wv = ev[S + idx]; idx++; }
        w[k * N_TOTAL + j] = wv;
    }
}

// One simulation step, fused: syn gather + neuron update + STDP.
// w double-buffered: reads w_old (all planes), writes w_new (own column j).
// Plane-major layout -> every w access is wave-coalesced.
__global__ __launch_bounds__(256) void step_kernel(
    const float* __restrict__ xext,      // external_input + t*N (read-once)
    const float* __restrict__ w_old,
    float* __restrict__ w_new,
    const float* __restrict__ prev,      // out of previous step
    float* __restrict__ out,
    float* __restrict__ v,
    float* __restrict__ spk,             // d_out + t*N (write-only)
    int t) {
#pragma clang fp contract(off)
    int j = blockIdx.x * 256 + threadIdx.x;
    int z = j & 63, y = (j >> 6) & 63, x = j >> 12;

    float pv[KOFF];
    float syn = 0.0f;
    if (t == 0) {
        // prev == 0 at step 0; buffers unread (poisoned) -> skip gather.
#pragma unroll
        for (int k = 0; k < KOFF; k++) pv[k] = 0.0f;
    } else {
#pragma unroll
        for (int k = 0; k < KOFF; k++) {
            int nx = x + DXc[k], ny = y + DYc[k], nz = z + DZc[k];
            bool ok = ((unsigned)nx < 64u) & ((unsigned)ny < 64u) &
                      ((unsigned)nz < 64u);
            int nb = j + DLc[k];
            float p = 0.0f, wv = 0.0f;
            if (ok) {
                p = prev[nb];
                wv = w_old[(23 - k) * N_TOTAL + nb];  // edge (nb -> j)
            }
            pv[k] = p;
            float m = wv * p;     // contract(off): mul then add, like numpy
            syn = syn + m;        // ascending-row order == segment_sum order
        }
    }

    float myv = (t == 0) ? -65.0f : v[j];
    const float decay = expf(-1.0f / 20.0f);
    float I = syn + __builtin_nontemporal_load(xext + j);
    float vn = (myv * decay) + (I * (1.0f - decay));
    float spike = (vn >= -50.0f) ? 1.0f : 0.0f;
    float inhib = (vn <= -70.0f) ? 1.0f : 0.0f;
    float sg = 1.0f / (1.0f + expf(-((vn - (-60.0f)) * 0.5f)));
    float o = spike + ((1.0f - spike) * (1.0f - inhib)) * sg;
    v[j] = (vn * (1.0f - spike)) + (spike * (-65.0f));
    out[j] = o;
    __builtin_nontemporal_store(spike, spk + j);

    // STDP on row j's edges: pre = prev[col] = pv[k], post = out[j] = o.
    // Invalid slots: wv==0 && pv==0 -> dw==0 -> stays 0. No masking needed.
#pragma unroll
    for (int k = 0; k < KOFF; k++) {
        float wv = w_old[k * N_TOTAL + j];
        float nw;
        if (t == 0) {
            nw = wv;  // reference skips plasticity at step 0
        } else {
            float pre = pv[k];
            float a = (0.01f * pre) * o;
            float b = (0.005f * pre) * (1.0f - o);
            float c = 1e-5f * wv;
            float dw = (a - b) - c;
            nw = wv + dw;
            nw = fminf(fmaxf(nw, 0.0f), 1.0f);
        }
        w_new[k * N_TOTAL + j] = nw;
    }
}

extern "C" void kernel_launch(void* const* d_in, const int* in_sizes, int n_in,
                              void* d_out, int out_size, void* d_ws, size_t ws_size,
                              hipStream_t stream) {
    const float* xext = (const float*)d_in[0];
    const float* ev   = (const float*)d_in[1];
    float* spk = (float*)d_out;

    int T = in_sizes[0] / N_TOTAL;   // 50

    // Workspace layout: w0 | w1 | P0 | P1 | v  -> (2*24 + 3) * N floats ≈ 53.5 MB
    float* w0 = (float*)d_ws;
    float* w1 = w0 + (size_t)N_TOTAL * KOFF;
    float* P0 = w1 + (size_t)N_TOTAL * KOFF;
    float* P1 = P0 + N_TOTAL;
    float* vb = P1 + N_TOTAL;

    pack_w_kernel<<<N_TOTAL / 256, 256, 0, stream>>>(ev, w0);

    for (int t = 0; t < T; t++) {
        const float* wo = (t & 1) ? w1 : w0;
        float*       wn = (t & 1) ? w0 : w1;
        const float* pr = (t & 1) ? P1 : P0;
        float*       po = (t & 1) ? P0 : P1;
        step_kernel<<<N_TOTAL / 256, 256, 0, stream>>>(
            xext + (size_t)t * N_TOTAL, wo, wn, pr, po, vb,
            spk + (size_t)t * N_TOTAL, t);
    }
}